// Round 6
// baseline (435.728 us; speedup 1.0000x reference)
//
#include <hip/hip_runtime.h>
#include <math.h>

#define D 64

// ---------------- K2: logits (16 lanes x float4 per edge, 8 edges/wave/iter) ----------------
// Emits packed per-edge records {logit, scale=na_e*ye, dst=idx*N+vj, segid} for K3.
// Also zeroes out[] and row_sum[] in its prologue, writes seg_start sentinel.
__global__ __launch_bounds__(256, 8) void k_logits(
    const int* __restrict__ sel, const float* __restrict__ hc,
    const float* __restrict__ hu, const float* __restrict__ re,
    const float* __restrict__ wsm, const float* __restrict__ bias,
    const float* __restrict__ out_w, const float* __restrict__ out_b,
    const float* __restrict__ na, const float* __restrict__ ey,
    int4* __restrict__ rec, int* __restrict__ seg_start,
    float* __restrict__ out, float* __restrict__ row_sum,
    int E, int N, int BN, int Bn)
{
    const int tid = blockIdx.x * 256 + threadIdx.x;
    const int nthreads = gridDim.x * 256;

    // prologue: zero output + row sums (used by K3/K5; kernel boundary orders it)
    for (int i = tid; i < BN; i += nthreads) out[i] = 0.f;
    if (tid < Bn) row_sum[tid] = 0.f;

    const int lane = threadIdx.x & 63;
    const int g    = lane >> 4;    // edge-group within wave (0..3)
    const int d16  = lane & 15;    // lane within group; covers d = d16*4 .. d16*4+3

    // hoist constants into registers (amortized over grid-stride loop)
    const float4* wsm4 = (const float4*)wsm;
    float4 W[8];
    #pragma unroll
    for (int k = 0; k < 8; ++k) W[k] = wsm4[k * 16 + d16];
    const float4 Bv = ((const float4*)bias)[d16];
    const float4 Ow = ((const float4*)out_w)[d16];
    const float4 Ob = ((const float4*)out_b)[d16];
    const float* Wf  = (const float*)W;
    const float* Bvf = (const float*)&Bv;
    const float* Owf = (const float*)&Ow;
    const float* Obf = (const float*)&Ob;

    const float4* hc4 = (const float4*)hc;
    const float4* hu4 = (const float4*)hu;
    const float4* re4 = (const float4*)re;

    const int wave   = tid >> 6;
    const int nwaves = nthreads >> 6;
    const int octs   = (E + 7) >> 3;

    for (int q = wave; q < octs; q += nwaves) {
        const int e0 = q * 8 + g;
        const int e1 = q * 8 + 4 + g;
        const bool v0 = (e0 < E);
        const bool v1 = (e1 < E);
        const int ec0 = v0 ? e0 : (E - 1);
        const int ec1 = v1 ? e1 : (E - 1);

        // index loads
        const int4 sA0 = *(const int4*)(sel + (size_t)ec0 * 8);
        const int4 sB0 = *(const int4*)(sel + (size_t)ec0 * 8 + 4);
        const int4 sA1 = *(const int4*)(sel + (size_t)ec1 * 8);
        const int4 sB1 = *(const int4*)(sel + (size_t)ec1 * 8 + 4);

        // issue all 10 row-gathers (independent -> deep VMEM queue)
        const float4 a0  = hc4[(size_t)sB0.z * 16 + d16];
        const float4 c0  = hc4[(size_t)sB0.w * 16 + d16];
        const float4 ui0 = hu4[(size_t)sA0.y * 16 + d16];
        const float4 uj0 = hu4[(size_t)sA0.z * 16 + d16];
        const float4 r0  = re4[(size_t)sA0.w * 16 + d16];
        const float4 a1  = hc4[(size_t)sB1.z * 16 + d16];
        const float4 c1  = hc4[(size_t)sB1.w * 16 + d16];
        const float4 ui1 = hu4[(size_t)sA1.y * 16 + d16];
        const float4 uj1 = hu4[(size_t)sA1.z * 16 + d16];
        const float4 r1  = re4[(size_t)sA1.w * 16 + d16];

        // record-side scalars (one lane per group; vi-sorted -> near-sequential)
        float ye0 = 0.f, ye1 = 0.f, nae0 = 0.f, nae1 = 0.f;
        if (d16 == 0) {
            ye0  = ey[ec0];
            ye1  = ey[ec1];
            nae0 = na[(size_t)sA0.x * N + sA0.y];
            nae1 = na[(size_t)sA1.x * N + sA1.y];
        }

        float acc0 = 0.f, acc1 = 0.f;
        {
            const float* ap = (const float*)&a0;  const float* cp = (const float*)&c0;
            const float* up = (const float*)&ui0; const float* vp = (const float*)&uj0;
            const float* rp = (const float*)&r0;
            #pragma unroll
            for (int k4 = 0; k4 < 4; ++k4) {
                const float hcvi = ap[k4], hcvj = cp[k4], huvi = up[k4], huvj = vp[k4], rr = rp[k4];
                const float p = hcvi * hcvj, qq = hcvi * huvj, ss = huvi * hcvj, uu = huvi * huvj;
                const float w01 = fmaf(rr, Wf[1*4+k4], Wf[0*4+k4]);
                const float w23 = fmaf(rr, Wf[3*4+k4], Wf[2*4+k4]);
                const float w45 = fmaf(rr, Wf[5*4+k4], Wf[4*4+k4]);
                const float w67 = fmaf(rr, Wf[7*4+k4], Wf[6*4+k4]);
                float f = fmaf(p, w01, Bvf[k4]);
                f = fmaf(qq, w23, f);
                f = fmaf(ss, w45, f);
                f = fmaf(uu, w67, f);
                acc0 += fmaf(fmaxf(f, 0.f), Owf[k4], Obf[k4]);
            }
        }
        {
            const float* ap = (const float*)&a1;  const float* cp = (const float*)&c1;
            const float* up = (const float*)&ui1; const float* vp = (const float*)&uj1;
            const float* rp = (const float*)&r1;
            #pragma unroll
            for (int k4 = 0; k4 < 4; ++k4) {
                const float hcvi = ap[k4], hcvj = cp[k4], huvi = up[k4], huvj = vp[k4], rr = rp[k4];
                const float p = hcvi * hcvj, qq = hcvi * huvj, ss = huvi * hcvj, uu = huvi * huvj;
                const float w01 = fmaf(rr, Wf[1*4+k4], Wf[0*4+k4]);
                const float w23 = fmaf(rr, Wf[3*4+k4], Wf[2*4+k4]);
                const float w45 = fmaf(rr, Wf[5*4+k4], Wf[4*4+k4]);
                const float w67 = fmaf(rr, Wf[7*4+k4], Wf[6*4+k4]);
                float f = fmaf(p, w01, Bvf[k4]);
                f = fmaf(qq, w23, f);
                f = fmaf(ss, w45, f);
                f = fmaf(uu, w67, f);
                acc1 += fmaf(fmaxf(f, 0.f), Owf[k4], Obf[k4]);
            }
        }

        // reduce across the 16 lanes of each group
        #pragma unroll
        for (int off = 8; off > 0; off >>= 1) {
            acc0 += __shfl_xor(acc0, off, 64);
            acc1 += __shfl_xor(acc1, off, 64);
        }

        // previous-edge idx_vi via shuffles
        const int idxvi0 = sB0.x, idxvi1 = sB1.x;
        const int srcm16 = (lane >= 16) ? (lane - 16) : lane;
        const int p0w = __shfl(idxvi0, srcm16, 64);
        const int p1w = __shfl(idxvi1, srcm16, 64);
        const int p1b = __shfl(idxvi0, 48 + d16, 64);

        if (d16 == 0) {
            if (v0) {
                int4 rv;
                rv.x = __float_as_int(acc0);
                rv.y = __float_as_int(nae0 * ye0);
                rv.z = sA0.x * N + sA0.z;
                rv.w = idxvi0;
                rec[e0] = rv;
                int prev;
                if (e0 == 0)     prev = -1;
                else if (g == 0) prev = sel[(size_t)(e0 - 1) * 8 + 4];
                else             prev = p0w;
                if (idxvi0 != prev) seg_start[idxvi0] = e0;
                if (e0 == E - 1) seg_start[idxvi0 + 1] = E;   // sentinel
            }
            if (v1) {
                int4 rv;
                rv.x = __float_as_int(acc1);
                rv.y = __float_as_int(nae1 * ye1);
                rv.z = sA1.x * N + sA1.z;
                rv.w = idxvi1;
                rec[e1] = rv;
                const int prev = (g == 0) ? p1b : p1w;
                if (idxvi1 != prev) seg_start[idxvi1] = e1;
                if (e1 == E - 1) seg_start[idxvi1 + 1] = E;   // sentinel
            }
        }
    }
}

// ---------------- K3: edge-parallel softmax + scatter-add from packed records ----------------
__global__ __launch_bounds__(256) void k_softmax_scatter(
    const int4* __restrict__ rec, const int* __restrict__ seg_start,
    float* __restrict__ out, int E)
{
    const int e = blockIdx.x * 256 + threadIdx.x;
    if (e >= E) return;

    const int4 r = rec[e];
    const float myl   = __int_as_float(r.x);
    const float scale = __int_as_float(r.y);
    const int   dst   = r.z;
    const int   s     = r.w;
    const int start = seg_start[s];
    const int end   = seg_start[s + 1];                 // sentinel makes this valid

    float ta;
    if (end - start == 1) {
        ta = scale;                                     // exp(0)/1 == 1 exactly
    } else {
        float m = myl;
        for (int i = start; i < end; ++i)
            m = fmaxf(m, __int_as_float(rec[i].x));
        float sum = 0.f;
        for (int i = start; i < end; ++i)
            sum += __expf(__int_as_float(rec[i].x) - m);
        ta = scale * (__expf(myl - m) / sum);
    }
    atomicAdd(out + dst, ta);
}

// ---------------- K5: row sums of out (few blocks, LDS reduce, 64 total atomics) ----------
__global__ __launch_bounds__(256) void k_rowsum(
    const float4* __restrict__ out, float* __restrict__ row_sum, int N4)
{
    __shared__ float red[4];
    const int row = blockIdx.y;
    float s = 0.f;
    for (int i = blockIdx.x * 256 + threadIdx.x; i < N4; i += gridDim.x * 256) {
        const float4 v = out[(size_t)row * N4 + i];
        s += v.x + v.y + v.z + v.w;
    }
    #pragma unroll
    for (int off = 32; off > 0; off >>= 1)
        s += __shfl_xor(s, off, 64);
    if ((threadIdx.x & 63) == 0) red[threadIdx.x >> 6] = s;
    __syncthreads();
    if (threadIdx.x == 0)
        atomicAdd(row_sum + row, red[0] + red[1] + red[2] + red[3]);
}

// ---------------- K4: normalize rows (float4, 2D grid) ----------------
__global__ void k_norm(float4* __restrict__ out, const float* __restrict__ row_sum, int N4) {
    const int col = blockIdx.x * blockDim.x + threadIdx.x;
    const int row = blockIdx.y;
    if (col < N4) {
        const float inv = 1.f / row_sum[row];
        const size_t i = (size_t)row * N4 + col;
        float4 v = out[i];
        v.x *= inv; v.y *= inv; v.z *= inv; v.w *= inv;
        out[i] = v;
    }
}

extern "C" void kernel_launch(void* const* d_in, const int* in_sizes, int n_in,
                              void* d_out, int out_size, void* d_ws, size_t ws_size,
                              hipStream_t stream)
{
    const float* na    = (const float*)d_in[0];   // (B,N)
    const int*   sel   = (const int*)  d_in[1];   // (E,8)
    const float* ey    = (const float*)d_in[2];   // (E,)
    const float* hc    = (const float*)d_in[3];   // (n_visited, D)
    const float* hu    = (const float*)d_in[4];   // (1,N,D)
    const float* re    = (const float*)d_in[5];   // (R,D)
    const float* wsm   = (const float*)d_in[6];   // (8,D)
    const float* bias  = (const float*)d_in[7];   // (D,)
    const float* ow    = (const float*)d_in[8];   // (D,)
    const float* ob    = (const float*)d_in[9];   // (D,)
    // d_in[10] = n_vi_seg (replaced by seg_start sentinel); d_in[11] = n_vj_seg (unused)

    float* out = (float*)d_out;

    const int E  = in_sizes[2];
    const int N  = in_sizes[4] / D;   // hidden_uncon = N*D
    const int BN = in_sizes[0];       // B*N
    const int Bn = BN / N;

    // workspace: rec (E int4) | seg_start (E+1 ints) | row_sum (B floats, 256B-aligned)
    int4* rec        = (int4*)d_ws;
    int*  seg_start  = (int*) ((char*)d_ws + (size_t)E * 16);
    const size_t rs_off = (((size_t)E * 16 + (size_t)(E + 1) * 4) + 255) & ~(size_t)255;
    float* row_sum   = (float*)((char*)d_ws + rs_off);

    k_logits<<<2048, 256, 0, stream>>>(sel, hc, hu, re, wsm, bias, ow, ob, na, ey,
                                       rec, seg_start, out, row_sum, E, N, BN, Bn);
    k_softmax_scatter<<<(E + 255) / 256, 256, 0, stream>>>(rec, seg_start, out, E);
    const int N4 = N / 4;
    dim3 rgrid(16, Bn);
    k_rowsum<<<rgrid, 256, 0, stream>>>((const float4*)out, row_sum, N4);
    dim3 ngrid((N4 + 255) / 256, Bn);
    k_norm<<<ngrid, 256, 0, stream>>>((float4*)out, row_sum, N4);
}

// Round 7
// 163.113 us; speedup vs baseline: 2.6713x; 2.6713x over previous
//
#include <hip/hip_runtime.h>
#include <math.h>

#define D 64

// ---------------- K2: logits (16 lanes x float4 per edge, 8 edges/wave/iter) ----------------
// Emits packed per-edge records {logit, scale=na_e*ye, dst=idx*N+vj, segid} for K3.
// Also zeroes out[] and row_sum[] in its prologue, writes seg_start sentinel.
// NOTE: plain __launch_bounds__(256) — forcing 8 waves/SIMD caps VGPR at 32 and
// spills ~1 GB of scratch to HBM (R6: 45us -> 322us). 68 VGPR / ~4 waves is right.
__global__ __launch_bounds__(256) void k_logits(
    const int* __restrict__ sel, const float* __restrict__ hc,
    const float* __restrict__ hu, const float* __restrict__ re,
    const float* __restrict__ wsm, const float* __restrict__ bias,
    const float* __restrict__ out_w, const float* __restrict__ out_b,
    const float* __restrict__ na, const float* __restrict__ ey,
    int4* __restrict__ rec, int* __restrict__ seg_start,
    float* __restrict__ out, float* __restrict__ row_sum,
    int E, int N, int BN, int Bn)
{
    const int tid = blockIdx.x * 256 + threadIdx.x;
    const int nthreads = gridDim.x * 256;

    // prologue: zero output + row sums (used by K3/K5; kernel boundary orders it)
    for (int i = tid; i < BN; i += nthreads) out[i] = 0.f;
    if (tid < Bn) row_sum[tid] = 0.f;

    const int lane = threadIdx.x & 63;
    const int g    = lane >> 4;    // edge-group within wave (0..3)
    const int d16  = lane & 15;    // lane within group; covers d = d16*4 .. d16*4+3

    // hoist constants into registers (amortized over grid-stride loop)
    const float4* wsm4 = (const float4*)wsm;
    float4 W[8];
    #pragma unroll
    for (int k = 0; k < 8; ++k) W[k] = wsm4[k * 16 + d16];
    const float4 Bv = ((const float4*)bias)[d16];
    const float4 Ow = ((const float4*)out_w)[d16];
    const float4 Ob = ((const float4*)out_b)[d16];
    const float* Wf  = (const float*)W;
    const float* Bvf = (const float*)&Bv;
    const float* Owf = (const float*)&Ow;
    const float* Obf = (const float*)&Ob;

    const float4* hc4 = (const float4*)hc;
    const float4* hu4 = (const float4*)hu;
    const float4* re4 = (const float4*)re;

    const int wave   = tid >> 6;
    const int nwaves = nthreads >> 6;
    const int octs   = (E + 7) >> 3;

    for (int q = wave; q < octs; q += nwaves) {
        const int e0 = q * 8 + g;
        const int e1 = q * 8 + 4 + g;
        const bool v0 = (e0 < E);
        const bool v1 = (e1 < E);
        const int ec0 = v0 ? e0 : (E - 1);
        const int ec1 = v1 ? e1 : (E - 1);

        // index loads
        const int4 sA0 = *(const int4*)(sel + (size_t)ec0 * 8);
        const int4 sB0 = *(const int4*)(sel + (size_t)ec0 * 8 + 4);
        const int4 sA1 = *(const int4*)(sel + (size_t)ec1 * 8);
        const int4 sB1 = *(const int4*)(sel + (size_t)ec1 * 8 + 4);

        // issue all 10 row-gathers (independent -> deep VMEM queue)
        const float4 a0  = hc4[(size_t)sB0.z * 16 + d16];
        const float4 c0  = hc4[(size_t)sB0.w * 16 + d16];
        const float4 ui0 = hu4[(size_t)sA0.y * 16 + d16];
        const float4 uj0 = hu4[(size_t)sA0.z * 16 + d16];
        const float4 r0  = re4[(size_t)sA0.w * 16 + d16];
        const float4 a1  = hc4[(size_t)sB1.z * 16 + d16];
        const float4 c1  = hc4[(size_t)sB1.w * 16 + d16];
        const float4 ui1 = hu4[(size_t)sA1.y * 16 + d16];
        const float4 uj1 = hu4[(size_t)sA1.z * 16 + d16];
        const float4 r1  = re4[(size_t)sA1.w * 16 + d16];

        // record-side scalars (one lane per group; vi-sorted -> near-sequential)
        float ye0 = 0.f, ye1 = 0.f, nae0 = 0.f, nae1 = 0.f;
        if (d16 == 0) {
            ye0  = ey[ec0];
            ye1  = ey[ec1];
            nae0 = na[(size_t)sA0.x * N + sA0.y];
            nae1 = na[(size_t)sA1.x * N + sA1.y];
        }

        float acc0 = 0.f, acc1 = 0.f;
        {
            const float* ap = (const float*)&a0;  const float* cp = (const float*)&c0;
            const float* up = (const float*)&ui0; const float* vp = (const float*)&uj0;
            const float* rp = (const float*)&r0;
            #pragma unroll
            for (int k4 = 0; k4 < 4; ++k4) {
                const float hcvi = ap[k4], hcvj = cp[k4], huvi = up[k4], huvj = vp[k4], rr = rp[k4];
                const float p = hcvi * hcvj, qq = hcvi * huvj, ss = huvi * hcvj, uu = huvi * huvj;
                const float w01 = fmaf(rr, Wf[1*4+k4], Wf[0*4+k4]);
                const float w23 = fmaf(rr, Wf[3*4+k4], Wf[2*4+k4]);
                const float w45 = fmaf(rr, Wf[5*4+k4], Wf[4*4+k4]);
                const float w67 = fmaf(rr, Wf[7*4+k4], Wf[6*4+k4]);
                float f = fmaf(p, w01, Bvf[k4]);
                f = fmaf(qq, w23, f);
                f = fmaf(ss, w45, f);
                f = fmaf(uu, w67, f);
                acc0 += fmaf(fmaxf(f, 0.f), Owf[k4], Obf[k4]);
            }
        }
        {
            const float* ap = (const float*)&a1;  const float* cp = (const float*)&c1;
            const float* up = (const float*)&ui1; const float* vp = (const float*)&uj1;
            const float* rp = (const float*)&r1;
            #pragma unroll
            for (int k4 = 0; k4 < 4; ++k4) {
                const float hcvi = ap[k4], hcvj = cp[k4], huvi = up[k4], huvj = vp[k4], rr = rp[k4];
                const float p = hcvi * hcvj, qq = hcvi * huvj, ss = huvi * hcvj, uu = huvi * huvj;
                const float w01 = fmaf(rr, Wf[1*4+k4], Wf[0*4+k4]);
                const float w23 = fmaf(rr, Wf[3*4+k4], Wf[2*4+k4]);
                const float w45 = fmaf(rr, Wf[5*4+k4], Wf[4*4+k4]);
                const float w67 = fmaf(rr, Wf[7*4+k4], Wf[6*4+k4]);
                float f = fmaf(p, w01, Bvf[k4]);
                f = fmaf(qq, w23, f);
                f = fmaf(ss, w45, f);
                f = fmaf(uu, w67, f);
                acc1 += fmaf(fmaxf(f, 0.f), Owf[k4], Obf[k4]);
            }
        }

        // reduce across the 16 lanes of each group
        #pragma unroll
        for (int off = 8; off > 0; off >>= 1) {
            acc0 += __shfl_xor(acc0, off, 64);
            acc1 += __shfl_xor(acc1, off, 64);
        }

        // previous-edge idx_vi via shuffles
        const int idxvi0 = sB0.x, idxvi1 = sB1.x;
        const int srcm16 = (lane >= 16) ? (lane - 16) : lane;
        const int p0w = __shfl(idxvi0, srcm16, 64);
        const int p1w = __shfl(idxvi1, srcm16, 64);
        const int p1b = __shfl(idxvi0, 48 + d16, 64);

        if (d16 == 0) {
            if (v0) {
                int4 rv;
                rv.x = __float_as_int(acc0);
                rv.y = __float_as_int(nae0 * ye0);
                rv.z = sA0.x * N + sA0.z;
                rv.w = idxvi0;
                rec[e0] = rv;
                int prev;
                if (e0 == 0)     prev = -1;
                else if (g == 0) prev = sel[(size_t)(e0 - 1) * 8 + 4];
                else             prev = p0w;
                if (idxvi0 != prev) seg_start[idxvi0] = e0;
                if (e0 == E - 1) seg_start[idxvi0 + 1] = E;   // sentinel
            }
            if (v1) {
                int4 rv;
                rv.x = __float_as_int(acc1);
                rv.y = __float_as_int(nae1 * ye1);
                rv.z = sA1.x * N + sA1.z;
                rv.w = idxvi1;
                rec[e1] = rv;
                const int prev = (g == 0) ? p1b : p1w;
                if (idxvi1 != prev) seg_start[idxvi1] = e1;
                if (e1 == E - 1) seg_start[idxvi1 + 1] = E;   // sentinel
            }
        }
    }
}

// ---------------- K3: edge-parallel softmax + scatter-add from packed records ----------------
__global__ __launch_bounds__(256) void k_softmax_scatter(
    const int4* __restrict__ rec, const int* __restrict__ seg_start,
    float* __restrict__ out, int E)
{
    const int e = blockIdx.x * 256 + threadIdx.x;
    if (e >= E) return;

    const int4 r = rec[e];
    const float myl   = __int_as_float(r.x);
    const float scale = __int_as_float(r.y);
    const int   dst   = r.z;
    const int   s     = r.w;
    const int start = seg_start[s];
    const int end   = seg_start[s + 1];                 // sentinel makes this valid

    float ta;
    if (end - start == 1) {
        ta = scale;                                     // exp(0)/1 == 1 exactly
    } else {
        float m = myl;
        for (int i = start; i < end; ++i)
            m = fmaxf(m, __int_as_float(rec[i].x));
        float sum = 0.f;
        for (int i = start; i < end; ++i)
            sum += __expf(__int_as_float(rec[i].x) - m);
        ta = scale * (__expf(myl - m) / sum);
    }
    atomicAdd(out + dst, ta);
}

// ---------------- K5: row sums of out (few blocks, LDS reduce, 64 total atomics) ----------
__global__ __launch_bounds__(256) void k_rowsum(
    const float4* __restrict__ out, float* __restrict__ row_sum, int N4)
{
    __shared__ float red[4];
    const int row = blockIdx.y;
    float s = 0.f;
    for (int i = blockIdx.x * 256 + threadIdx.x; i < N4; i += gridDim.x * 256) {
        const float4 v = out[(size_t)row * N4 + i];
        s += v.x + v.y + v.z + v.w;
    }
    #pragma unroll
    for (int off = 32; off > 0; off >>= 1)
        s += __shfl_xor(s, off, 64);
    if ((threadIdx.x & 63) == 0) red[threadIdx.x >> 6] = s;
    __syncthreads();
    if (threadIdx.x == 0)
        atomicAdd(row_sum + row, red[0] + red[1] + red[2] + red[3]);
}

// ---------------- K4: normalize rows (float4, 2D grid) ----------------
__global__ void k_norm(float4* __restrict__ out, const float* __restrict__ row_sum, int N4) {
    const int col = blockIdx.x * blockDim.x + threadIdx.x;
    const int row = blockIdx.y;
    if (col < N4) {
        const float inv = 1.f / row_sum[row];
        const size_t i = (size_t)row * N4 + col;
        float4 v = out[i];
        v.x *= inv; v.y *= inv; v.z *= inv; v.w *= inv;
        out[i] = v;
    }
}

extern "C" void kernel_launch(void* const* d_in, const int* in_sizes, int n_in,
                              void* d_out, int out_size, void* d_ws, size_t ws_size,
                              hipStream_t stream)
{
    const float* na    = (const float*)d_in[0];   // (B,N)
    const int*   sel   = (const int*)  d_in[1];   // (E,8)
    const float* ey    = (const float*)d_in[2];   // (E,)
    const float* hc    = (const float*)d_in[3];   // (n_visited, D)
    const float* hu    = (const float*)d_in[4];   // (1,N,D)
    const float* re    = (const float*)d_in[5];   // (R,D)
    const float* wsm   = (const float*)d_in[6];   // (8,D)
    const float* bias  = (const float*)d_in[7];   // (D,)
    const float* ow    = (const float*)d_in[8];   // (D,)
    const float* ob    = (const float*)d_in[9];   // (D,)
    // d_in[10] = n_vi_seg (replaced by seg_start sentinel); d_in[11] = n_vj_seg (unused)

    float* out = (float*)d_out;

    const int E  = in_sizes[2];
    const int N  = in_sizes[4] / D;   // hidden_uncon = N*D
    const int BN = in_sizes[0];       // B*N
    const int Bn = BN / N;

    // workspace: rec (E int4) | seg_start (E+1 ints) | row_sum (B floats, 256B-aligned)
    int4* rec        = (int4*)d_ws;
    int*  seg_start  = (int*) ((char*)d_ws + (size_t)E * 16);
    const size_t rs_off = (((size_t)E * 16 + (size_t)(E + 1) * 4) + 255) & ~(size_t)255;
    float* row_sum   = (float*)((char*)d_ws + rs_off);

    k_logits<<<2048, 256, 0, stream>>>(sel, hc, hu, re, wsm, bias, ow, ob, na, ey,
                                       rec, seg_start, out, row_sum, E, N, BN, Bn);
    k_softmax_scatter<<<(E + 255) / 256, 256, 0, stream>>>(rec, seg_start, out, E);
    const int N4 = N / 4;
    dim3 rgrid(16, Bn);
    k_rowsum<<<rgrid, 256, 0, stream>>>((const float4*)out, row_sum, N4);
    dim3 ngrid((N4 + 255) / 256, Bn);
    k_norm<<<ngrid, 256, 0, stream>>>((float4*)out, row_sum, N4);
}